// Round 13
// baseline (1005.250 us; speedup 1.0000x reference)
//
#include <hip/hip_runtime.h>
#include <math.h>

// Problem constants
#define F_DIM 321
#define H_DIM 4200
#define T_DIM 1000
#define NBC   16      // B*C = 8*2
#define KTOP  3
#define PADV  1e-8f
#define NSPLIT 4

// GEMM tiling: BK=16 -> LDS 44 KB -> 3 blocks/CU = 12 waves/CU (r12 was 2
// waves/SIMD latency-bound: LDS busy 42%, VALU 40%, neither saturated).
#define BM 128        // h rows per block tile
#define BN 128        // t cols per block tile
#define BK 16
#define LDA 16        // A row stride (words); XOR swizzle on write AND read
#define LDB 128       // B row stride (words)
#define NHT 33        // ceil(H_DIM / BM)
#define NKT 20        // k-tiles of 16 covering k=0..319 (tail k=320 separate)

typedef float v4f __attribute__((ext_vector_type(4)));

__device__ __forceinline__ void ins3(float v, int i,
                                     float& v0, float& v1, float& v2,
                                     int& i0, int& i1, int& i2) {
  // strict '>' keeps earlier (smaller-h) entries ahead on ties == lax.top_k
  if (v > v0)      { v2 = v1; i2 = i1; v1 = v0; i1 = i0; v0 = v; i0 = i; }
  else if (v > v1) { v2 = v1; i2 = i1; v1 = v;  i1 = i; }
  else if (v > v2) { v2 = v;  i2 = i; }
}

// K1: fused fp32 GEMM (nominee = integral_m @ mag[bc]) + running top-3 over h.
// Reg-staged prefetch pipeline (issue loads -> compute -> ds_write -> one
// barrier per kt). BK=16 for 3 blocks/CU; no occupancy attribute (live ~115
// fits the default allocator's <=128 pick; r6-r10 showed forced caps spill).
__global__ __launch_bounds__(256)
void hi_k1_gemm_top3(const float* __restrict__ mag,
                     const float* __restrict__ im,
                     float* __restrict__ wv, int* __restrict__ wi) {
  const int tid = threadIdx.x;
  const int tx = tid & 15;
  const int ty = tid >> 4;        // 16 row-groups of 8
  const int t0 = blockIdx.x * BN;
  const int bc = blockIdx.y;
  const int sp = blockIdx.z;
  const int ht_begin = (sp * NHT) / NSPLIT;
  const int ht_end   = ((sp + 1) * NHT) / NSPLIT;
  const int row0 = ty * 8;
  const int xsw = (ty & 3) << 2;  // A bank swizzle for this thread's rows
  const int wvi = tid >> 6;       // wave index 0..3

  __shared__ __align__(16) float As[2][BM * LDA];  // [h][k^swz], dbuf (8 KB ea)
  __shared__ __align__(16) float Bs[2][BK * LDB];  // [k][t], dbuf (8 KB ea)
  __shared__ float mv[4 * BN * KTOP];              // merge scratch (separate)
  __shared__ int   mi[4 * BN * KTOP];

  const float* magbc = mag + (size_t)bc * F_DIM * T_DIM;

  float ar[8];    // staged A words
  v4f   br[2];    // staged B v4fs

  // issue global loads for tile (nh0, nk0) into registers (no waiting)
  auto gload = [&](int nh0, int nk0) {
#pragma unroll
    for (int l = 0; l < 8; ++l) {
      int gh = nh0 + (tid >> 4) + 16 * l;
      gh = (gh < H_DIM) ? gh : (H_DIM - 1);   // clamp: dup row, masked later
      ar[l] = im[(size_t)gh * F_DIM + nk0 + (tid & 15)];
    }
#pragma unroll
    for (int l = 0; l < 2; ++l)
      // t-overrun of last tile reads into next k-row (in-bounds, masked later)
      br[l] = *(const v4f*)(magbc + (size_t)(nk0 + (tid >> 5) + 8 * l) * T_DIM
                            + t0 + 4 * (tid & 31));
  };
  // write staged regs into LDS buffer `buf` (compiler inserts vmcnt waits)
  auto dswrite = [&](int buf) {
#pragma unroll
    for (int l = 0; l < 8; ++l) {
      int hh = (tid >> 4) + 16 * l;
      As[buf][hh * LDA + ((tid & 15) ^ (((hh >> 3) & 3) << 2))] = ar[l];
    }
#pragma unroll
    for (int l = 0; l < 2; ++l)
      *(v4f*)(&Bs[buf][((tid >> 5) + 8 * l) * LDB + 4 * (tid & 31)]) = br[l];
  };

  float gv0 = -INFINITY, gv1 = -INFINITY, gv2 = -INFINITY;
  int   gi0 = 0, gi1 = 0, gi2 = 0;

  int cur = 0;
  gload(ht_begin * BM, 0);
  dswrite(0);
  __syncthreads();

  for (int ht = ht_begin; ht < ht_end; ++ht) {
    const int h0 = ht * BM;
    float acc[8][8];
#pragma unroll
    for (int r = 0; r < 8; ++r)
#pragma unroll
      for (int c = 0; c < 8; ++c) acc[r][c] = 0.f;

    for (int kt = 0; kt < NKT; ++kt) {
      // 1) issue next tile's global loads (this ht's kt+1, or next ht's kt 0)
      bool have_next = true;
      int nh0 = h0, nk0 = (kt + 1) * BK;
      if (kt == NKT - 1) {
        if (ht + 1 < ht_end) { nh0 = h0 + BM; nk0 = 0; }
        else have_next = false;
      }
      if (have_next) gload(nh0, nk0);

      // 2) compute current buffer: 4 groups of 4 k
#pragma unroll 1
      for (int g = 0; g < 4; ++g) {
        v4f Bv[8];
#pragma unroll
        for (int kk = 0; kk < 4; ++kk) {
          Bv[kk * 2]     = *(const v4f*)(&Bs[cur][(g * 4 + kk) * LDB + tx * 4]);
          Bv[kk * 2 + 1] = *(const v4f*)(&Bs[cur][(g * 4 + kk) * LDB + 64 + tx * 4]);
        }
#pragma unroll
        for (int r = 0; r < 8; ++r) {
          const v4f Ar = *(const v4f*)(&As[cur][(row0 + r) * LDA + ((g * 4) ^ xsw)]);
#pragma unroll
          for (int kk = 0; kk < 4; ++kk)
#pragma unroll
            for (int c = 0; c < 4; ++c) {
              acc[r][c]     = fmaf(Ar[kk], Bv[kk * 2][c],     acc[r][c]);
              acc[r][c + 4] = fmaf(Ar[kk], Bv[kk * 2 + 1][c], acc[r][c + 4]);
            }
        }
      }

      // 3) land staged tile in the other buffer; 4) one barrier per kt
      if (have_next) dswrite(cur ^ 1);
      __syncthreads();
      cur ^= 1;
    }

    // K tail: k = 320 (single column), straight from global (L2-resident)
    {
      float bt[8];
#pragma unroll
      for (int c = 0; c < 8; ++c) {
        int gt = t0 + ((c < 4) ? (tx * 4 + c) : (64 + tx * 4 + c - 4));
        bt[c] = (gt < T_DIM) ? magbc[(size_t)(F_DIM - 1) * T_DIM + gt] : 0.f;
      }
#pragma unroll
      for (int r = 0; r < 8; ++r) {
        int gh = h0 + row0 + r;
        float a = (gh < H_DIM) ? im[(size_t)gh * F_DIM + (F_DIM - 1)] : 0.f;
#pragma unroll
        for (int c = 0; c < 8; ++c) acc[r][c] = fmaf(a, bt[c], acc[r][c]);
      }
    }

    // per-column top-3 over own 8 rows (h ascending), then merge the 4
    // ty-bands in each wave (shfl_down 16 then 32 keeps ascending-h order)
#pragma unroll
    for (int c = 0; c < 8; ++c) {
      const int col = (c < 4) ? (tx * 4 + c) : (64 + tx * 4 + c - 4);
      float v0 = -INFINITY, v1 = -INFINITY, v2 = -INFINITY;
      int   i0 = 0, i1 = 0, i2 = 0;
#pragma unroll
      for (int r = 0; r < 8; ++r) {
        int gh = h0 + row0 + r;
        float v = (gh < H_DIM) ? acc[r][c] : -INFINITY;
        ins3(v, gh, v0, v1, v2, i0, i1, i2);
      }
#pragma unroll
      for (int s = 0; s < 2; ++s) {
        const int off = 16 << s;
        float ov0 = __shfl_down(v0, off);
        float ov1 = __shfl_down(v1, off);
        float ov2 = __shfl_down(v2, off);
        int   oi0 = __shfl_down(i0, off);
        int   oi1 = __shfl_down(i1, off);
        int   oi2 = __shfl_down(i2, off);
        ins3(ov0, oi0, v0, v1, v2, i0, i1, i2);
        ins3(ov1, oi1, v0, v1, v2, i0, i1, i2);
        ins3(ov2, oi2, v0, v1, v2, i0, i1, i2);
      }
      if ((ty & 3) == 0) {
        mv[(wvi * BN + col) * 3 + 0] = v0;
        mv[(wvi * BN + col) * 3 + 1] = v1;
        mv[(wvi * BN + col) * 3 + 2] = v2;
        mi[(wvi * BN + col) * 3 + 0] = i0;
        mi[(wvi * BN + col) * 3 + 1] = i1;
        mi[(wvi * BN + col) * 3 + 2] = i2;
      }
    }
    __syncthreads();
    // threads 0..127 own one column; merge 4 wave-lists (ascending h bands)
    if (tid < BN) {
#pragma unroll
      for (int w = 0; w < 4; ++w)
#pragma unroll
        for (int j = 0; j < 3; ++j) {
          float v = mv[(w * BN + tid) * 3 + j];
          int   i = mi[(w * BN + tid) * 3 + j];
          ins3(v, i, gv0, gv1, gv2, gi0, gi1, gi2);
        }
    }
  }

  if (tid < BN) {
    int t = t0 + tid;
    if (t < T_DIM) {
      size_t base = ((size_t)(bc * NSPLIT + sp) * KTOP) * T_DIM + t;
      wv[base]             = gv0;
      wv[base + T_DIM]     = gv1;
      wv[base + 2 * T_DIM] = gv2;
      wi[base]             = gi0;
      wi[base + T_DIM]     = gi1;
      wi[base + 2 * T_DIM] = gi2;
    }
  }
}

// K3: merge the NSPLIT partial top-3 lists, causal-pool the indices, gather
// harmonic_loc rows, sum over K, threshold, write (B,C,F,T) coalesced.
__global__ __launch_bounds__(256, 4)
void hi_k3_pool_gather(const float* __restrict__ wv, const int* __restrict__ wi,
                       const float* __restrict__ hl, float* __restrict__ out) {
  const int tid = threadIdx.x;
  const int t0 = blockIdx.x * 64;
  const int bc = blockIdx.y;

  __shared__ float pos_lds[66 * KTOP];   // t0-2 .. t0+63
  __shared__ int   rows[64 * KTOP];
  __shared__ float S[64 * 65];           // [t_local][f_chunk] transpose buffer

  if (tid < 66) {
    int t = t0 - 2 + tid;
    float p0 = PADV, p1 = PADV, p2 = PADV;
    if (t >= 0 && t < T_DIM) {
      float v0 = -INFINITY, v1 = -INFINITY, v2 = -INFINITY;
      int i0 = 0, i1 = 0, i2 = 0;
      for (int sp = 0; sp < NSPLIT; ++sp)        // ascending h ranges
        for (int j = 0; j < KTOP; ++j) {         // descending values
          size_t idx = ((size_t)(bc * NSPLIT + sp) * KTOP + j) * T_DIM + t;
          ins3(wv[idx], wi[idx], v0, v1, v2, i0, i1, i2);
        }
      p0 = (float)i0; p1 = (float)i1; p2 = (float)i2;
    }
    pos_lds[tid * KTOP + 0] = p0;
    pos_lds[tid * KTOP + 1] = p1;
    pos_lds[tid * KTOP + 2] = p2;
  }
  __syncthreads();
  if (tid < 64) {
#pragma unroll
    for (int k = 0; k < KTOP; ++k) {
      float s = (pos_lds[tid * KTOP + k] + pos_lds[(tid + 1) * KTOP + k])
                + pos_lds[(tid + 2) * KTOP + k];
      rows[tid * KTOP + k] = (int)(s / 3.0f);   // matches ref fp32 /3 + int cast
    }
  }
  __syncthreads();

  const int w = tid >> 6, lane = tid & 63;
  for (int fc = 0; fc < 6; ++fc) {
    const int f0 = fc * 64;
    for (int i = 0; i < 16; ++i) {
      int tl = w * 16 + i;
      int r0 = rows[tl * KTOP + 0];
      int r1 = rows[tl * KTOP + 1];
      int r2 = rows[tl * KTOP + 2];
      int f = f0 + lane;
      float s = 0.f;
      if (f < F_DIM)
        s = (hl[(size_t)r0 * F_DIM + f] + hl[(size_t)r1 * F_DIM + f])
            + hl[(size_t)r2 * F_DIM + f];
      S[tl * 65 + lane] = s;
    }
    __syncthreads();
#pragma unroll
    for (int i = 0; i < 16; ++i) {
      int e = tid + 256 * i;
      int fl = e >> 6, tl = e & 63;
      int f = f0 + fl, t = t0 + tl;
      if (f < F_DIM && t < T_DIM)
        out[((size_t)bc * F_DIM + f) * T_DIM + t] = (S[tl * 65 + fl] > 0.f) ? 1.f : 0.f;
    }
    __syncthreads();
  }
}

extern "C" void kernel_launch(void* const* d_in, const int* in_sizes, int n_in,
                              void* d_out, int out_size, void* d_ws, size_t ws_size,
                              hipStream_t stream) {
  const float* mag = (const float*)d_in[0];   // (8,2,321,1000)
  const float* im  = (const float*)d_in[1];   // (4200,321)
  const float* hl  = (const float*)d_in[2];   // (4200,321)
  float* out = (float*)d_out;                 // (8,2,321,1000)

  // ws layout: wv [16][NSPLIT][3][1000] floats, then wi same in ints (~1.5 MB)
  float* wv = (float*)d_ws;
  int*   wi = (int*)d_ws + (size_t)NBC * NSPLIT * KTOP * T_DIM;

  dim3 g1((T_DIM + BN - 1) / BN, NBC, NSPLIT);   // 8 x 16 x 4 = 512 blocks
  hipLaunchKernelGGL(hi_k1_gemm_top3, g1, dim3(256), 0, stream, mag, im, wv, wi);

  dim3 g3((T_DIM + 63) / 64, NBC);               // 16 x 16 = 256 blocks
  hipLaunchKernelGGL(hi_k3_pool_gather, g3, dim3(256), 0, stream, wv, wi, hl, out);
}